// Round 1
// baseline (1775.326 us; speedup 1.0000x reference)
//
#include <hip/hip_runtime.h>

#define NNZC   1000000
#define NPOI   100000
#define NEDGE  50000
#define NUSER  50000
#define DIM    128
#define NL     3

static inline int ceil_div(int a, int b) { return (a + b - 1) / b; }

// ---------------- softmax over the two 4-element attention vectors ----------------
__global__ void softmax4_kernel(const float* __restrict__ adi,
                                const float* __restrict__ amv,
                                float* __restrict__ w) {
    if (blockIdx.x == 0 && threadIdx.x == 0) {
        for (int b = 0; b < 2; b++) {
            const float* a = b ? amv : adi;
            float m = a[0];
            for (int l = 1; l < 4; l++) m = fmaxf(m, a[l]);
            float e[4]; float s = 0.f;
            for (int l = 0; l < 4; l++) { e[l] = __expf(a[l] - m); s += e[l]; }
            for (int l = 0; l < 4; l++) w[b * 4 + l] = e[l] / s;
        }
    }
}

// ---------------- CSR build: histogram -> scan -> fill ----------------
__global__ void hist_kernel(const int* __restrict__ rows, int* __restrict__ counts, int nnz) {
    int i = blockIdx.x * blockDim.x + threadIdx.x;
    if (i < nnz) atomicAdd(&counts[rows[i]], 1);
}

// per-block inclusive scan of counts chunk -> row_ptr[i+1] (partial), chunk totals -> bsums
__global__ void scanA_kernel(const int* __restrict__ counts, int* __restrict__ row_ptr,
                             int* __restrict__ bsums, int n) {
    __shared__ int s[256];
    int i = blockIdx.x * 256 + threadIdx.x;
    int v = (i < n) ? counts[i] : 0;
    s[threadIdx.x] = v;
    __syncthreads();
    for (int off = 1; off < 256; off <<= 1) {
        int t = (threadIdx.x >= (unsigned)off) ? s[threadIdx.x - off] : 0;
        __syncthreads();
        s[threadIdx.x] += t;
        __syncthreads();
    }
    if (i < n) row_ptr[i + 1] = s[threadIdx.x];
    if (threadIdx.x == 255) bsums[blockIdx.x] = s[255];
}

// exclusive scan of block sums (nb <= 512 guaranteed: max n = 100001 -> nb = 391)
__global__ void scanB_kernel(int* __restrict__ bsums, int nb) {
    __shared__ int s[512];
    int t = threadIdx.x;
    int v = (t < nb) ? bsums[t] : 0;
    s[t] = v;
    __syncthreads();
    for (int off = 1; off < 512; off <<= 1) {
        int u = (t >= off) ? s[t - off] : 0;
        __syncthreads();
        s[t] += u;
        __syncthreads();
    }
    if (t < nb) bsums[t] = s[t] - v;  // exclusive
}

// finalize row_ptr, derive per-row write cursor (= exclusive prefix)
__global__ void scanC_kernel(const int* __restrict__ counts, int* __restrict__ row_ptr,
                             const int* __restrict__ bsums, int* __restrict__ cursor, int n) {
    int i = blockIdx.x * 256 + threadIdx.x;
    if (i < n) {
        int f = row_ptr[i + 1] + bsums[blockIdx.x];
        row_ptr[i + 1] = f;
        cursor[i] = f - counts[i];
    }
    if (i == 0) row_ptr[0] = 0;
}

__global__ void fill_kernel(const int* __restrict__ rows, const int* __restrict__ cols,
                            const float* __restrict__ vals, int* __restrict__ cursor,
                            int* __restrict__ ccol, float* __restrict__ cval, int nnz) {
    int i = blockIdx.x * blockDim.x + threadIdx.x;
    if (i < nnz) {
        int r = rows[i];
        int pos = atomicAdd(&cursor[r], 1);
        ccol[pos] = cols[i];
        cval[pos] = vals[i];
    }
}

// ---------------- out = (w_di[0]+w_mv[0]) * pois ----------------
__global__ void init_out_kernel(const float* __restrict__ pois, float* __restrict__ out,
                                const float* __restrict__ w, int n) {
    int i = blockIdx.x * blockDim.x + threadIdx.x;
    if (i < n) out[i] = (w[0] + w[4]) * pois[i];
}

// ---------------- gather SpMM: one wave per output row, lanes cover D=128 as float2 ----------------
__global__ __launch_bounds__(256) void spmm_kernel(
    const int* __restrict__ row_ptr, const int* __restrict__ ccol,
    const float* __restrict__ cval, const float* __restrict__ x,
    float* __restrict__ y, int n_rows) {
    int wave = (blockIdx.x * blockDim.x + threadIdx.x) >> 6;
    int lane = threadIdx.x & 63;
    if (wave >= n_rows) return;
    int start = row_ptr[wave], end = row_ptr[wave + 1];
    float2 acc = make_float2(0.f, 0.f);
    for (int base = start; base < end; base += 64) {
        int idx = base + lane;
        int c = (idx < end) ? ccol[idx] : 0;
        float v = (idx < end) ? cval[idx] : 0.f;
        int nn = min(64, end - base);
        for (int j = 0; j < nn; j++) {
            int   cj = __shfl(c, j);
            float vj = __shfl(v, j);
            const float2 xr = *(const float2*)(x + (size_t)cj * DIM + lane * 2);
            acc.x = fmaf(vj, xr.x, acc.x);
            acc.y = fmaf(vj, xr.y, acc.y);
        }
    }
    *(float2*)(y + (size_t)wave * DIM + lane * 2) = acc;
}

// ---------------- fused second hop: x_new = relu(A2@m) + x_in; out += w * x_new ----------------
__global__ __launch_bounds__(256) void spmm_fused_kernel(
    const int* __restrict__ row_ptr, const int* __restrict__ ccol,
    const float* __restrict__ cval, const float* __restrict__ m,
    const float* __restrict__ xin, float* __restrict__ xout,
    float* __restrict__ out, const float* __restrict__ wptr, int widx, int n_rows) {
    int wave = (blockIdx.x * blockDim.x + threadIdx.x) >> 6;
    int lane = threadIdx.x & 63;
    if (wave >= n_rows) return;
    int start = row_ptr[wave], end = row_ptr[wave + 1];
    float2 acc = make_float2(0.f, 0.f);
    for (int base = start; base < end; base += 64) {
        int idx = base + lane;
        int c = (idx < end) ? ccol[idx] : 0;
        float v = (idx < end) ? cval[idx] : 0.f;
        int nn = min(64, end - base);
        for (int j = 0; j < nn; j++) {
            int   cj = __shfl(c, j);
            float vj = __shfl(v, j);
            const float2 mr = *(const float2*)(m + (size_t)cj * DIM + lane * 2);
            acc.x = fmaf(vj, mr.x, acc.x);
            acc.y = fmaf(vj, mr.y, acc.y);
        }
    }
    float w = wptr[widx];
    size_t o = (size_t)wave * DIM + lane * 2;
    float2 xi = *(const float2*)(xin + o);
    float2 xn;
    xn.x = fmaxf(acc.x, 0.f) + xi.x;
    xn.y = fmaxf(acc.y, 0.f) + xi.y;
    *(float2*)(xout + o) = xn;
    float2 ov = *(float2*)(out + o);
    ov.x = fmaf(w, xn.x, ov.x);
    ov.y = fmaf(w, xn.y, ov.y);
    *(float2*)(out + o) = ov;
}

extern "C" void kernel_launch(void* const* d_in, const int* in_sizes, int n_in,
                              void* d_out, int out_size, void* d_ws, size_t ws_size,
                              hipStream_t stream) {
    const float* pois = (const float*)d_in[0];
    const int*   rows_in[4] = { (const int*)d_in[1], (const int*)d_in[4],
                                (const int*)d_in[7], (const int*)d_in[10] };
    const int*   cols_in[4] = { (const int*)d_in[2], (const int*)d_in[5],
                                (const int*)d_in[8], (const int*)d_in[11] };
    const float* vals_in[4] = { (const float*)d_in[3], (const float*)d_in[6],
                                (const float*)d_in[9], (const float*)d_in[12] };
    const float* attn_di = (const float*)d_in[13];
    const float* attn_mv = (const float*)d_in[14];
    float* out = (float*)d_out;

    const int nrows[4] = { NEDGE, NPOI, NUSER, NPOI };  // tar, src, up, pu
    const int NTOT = NEDGE + NPOI + NUSER + NPOI;       // 300000

    // -------- workspace carve-up (all 4B types; blocks stay 16B-aligned) --------
    char* p = (char*)d_ws;
    float* wsoft = (float*)p;           p += 256;
    int* counts_all = (int*)p;          p += (size_t)NTOT * 4;
    int* cursor_all = (int*)p;          p += (size_t)NTOT * 4;
    int* rp_all = (int*)p;              p += (size_t)(NTOT + 4) * 4;
    int* bsums = (int*)p;               p += 512 * 4;
    int* ccol_all = (int*)p;            p += (size_t)4 * NNZC * 4;
    float* cval_all = (float*)p;        p += (size_t)4 * NNZC * 4;
    float* m1 = (float*)p;              p += (size_t)NEDGE * DIM * 4;
    float* xbuf = (float*)p;            p += (size_t)NPOI * DIM * 4;
    (void)ws_size; (void)out_size; (void)n_in; (void)in_sizes;

    int cnt_off[4], rp_off[4];
    { int c = 0, r = 0;
      for (int i = 0; i < 4; i++) { cnt_off[i] = c; rp_off[i] = r; c += nrows[i]; r += nrows[i] + 1; } }

    // -------- build CSR for the 4 incidence matrices --------
    hipMemsetAsync(counts_all, 0, (size_t)NTOT * 4, stream);
    const int gNNZ = ceil_div(NNZC, 256);
    for (int mtx = 0; mtx < 4; mtx++) {
        int n = nrows[mtx];
        int nb = ceil_div(n, 256);
        int* counts = counts_all + cnt_off[mtx];
        int* cursor = cursor_all + cnt_off[mtx];
        int* rp     = rp_all + rp_off[mtx];
        int* ccol   = ccol_all + (size_t)mtx * NNZC;
        float* cval = cval_all + (size_t)mtx * NNZC;
        hist_kernel<<<gNNZ, 256, 0, stream>>>(rows_in[mtx], counts, NNZC);
        scanA_kernel<<<nb, 256, 0, stream>>>(counts, rp, bsums, n);
        scanB_kernel<<<1, 512, 0, stream>>>(bsums, nb);
        scanC_kernel<<<nb, 256, 0, stream>>>(counts, rp, bsums, cursor, n);
        fill_kernel<<<gNNZ, 256, 0, stream>>>(rows_in[mtx], cols_in[mtx], vals_in[mtx],
                                              cursor, ccol, cval, NNZC);
    }

    // -------- layer-attention weights + output init --------
    softmax4_kernel<<<1, 64, 0, stream>>>(attn_di, attn_mv, wsoft);
    init_out_kernel<<<ceil_div(NPOI * DIM, 256), 256, 0, stream>>>(pois, out, wsoft, NPOI * DIM);

    // -------- the two branches: 3 layers of (A1 @ x) then fused (relu(A2 @ m) + x, out += w*x) --------
    for (int br = 0; br < 2; br++) {
        int m1i = br ? 2 : 0;   // up  : tar
        int m2i = br ? 3 : 1;   // pu  : src
        const int* rp1 = rp_all + rp_off[m1i];
        const int* rp2 = rp_all + rp_off[m2i];
        const int* cc1 = ccol_all + (size_t)m1i * NNZC;
        const int* cc2 = ccol_all + (size_t)m2i * NNZC;
        const float* cv1 = cval_all + (size_t)m1i * NNZC;
        const float* cv2 = cval_all + (size_t)m2i * NNZC;
        int n1 = nrows[m1i];
        const float* xcur = pois;
        for (int l = 1; l <= NL; l++) {
            spmm_kernel<<<ceil_div(n1, 4), 256, 0, stream>>>(rp1, cc1, cv1, xcur, m1, n1);
            spmm_fused_kernel<<<ceil_div(NPOI, 4), 256, 0, stream>>>(
                rp2, cc2, cv2, m1, xcur, xbuf, out, wsoft, br * 4 + l, NPOI);
            xcur = xbuf;
        }
    }
}

// Round 2
// 1262.896 us; speedup vs baseline: 1.4058x; 1.4058x over previous
//
#include <hip/hip_runtime.h>

#define NNZC   1000000
#define NPOI   100000
#define NEDGE  50000
#define NUSER  50000
#define DIM    128
#define NL     3

static inline int ceil_div(int a, int b) { return (a + b - 1) / b; }

typedef unsigned int uint32;

// ---- bf16 helpers: rows stored as packed pairs (uint32 = 2 bf16, little-endian) ----
__device__ __forceinline__ float bfLO(uint32 u) { return __uint_as_float(u << 16); }
__device__ __forceinline__ float bfHI(uint32 u) { return __uint_as_float(u & 0xffff0000u); }
__device__ __forceinline__ uint32 bf16_rne(float f) {
    uint32 u = __float_as_uint(f);
    return (u + 0x7fffu + ((u >> 16) & 1u)) >> 16;
}
__device__ __forceinline__ uint32 bfPACK(float a, float b) {
    return bf16_rne(a) | (bf16_rne(b) << 16);
}

// per-matrix constants: tar, src, up, pu
__device__ __constant__ const int c_nrows[4]  = { NEDGE, NPOI, NUSER, NPOI };
__device__ __constant__ const int c_cntoff[4] = { 0, NEDGE, NEDGE + NPOI, NEDGE + NPOI + NUSER };
__device__ __constant__ const int c_rpoff[4]  = { 0, NEDGE + 1, NEDGE + NPOI + 2, NEDGE + NPOI + NUSER + 3 };

// ---------------- softmax over the two 4-element attention vectors ----------------
__global__ void softmax4_kernel(const float* __restrict__ adi,
                                const float* __restrict__ amv,
                                float* __restrict__ w) {
    if (blockIdx.x == 0 && threadIdx.x == 0) {
        for (int b = 0; b < 2; b++) {
            const float* a = b ? amv : adi;
            float m = a[0];
            for (int l = 1; l < 4; l++) m = fmaxf(m, a[l]);
            float e[4]; float s = 0.f;
            for (int l = 0; l < 4; l++) { e[l] = __expf(a[l] - m); s += e[l]; }
            for (int l = 0; l < 4; l++) w[b * 4 + l] = e[l] / s;
        }
    }
}

// ---------------- merged CSR build: histogram -> scan -> fill (grid.y = matrix) ----------------
__global__ void hist4_kernel(const int* __restrict__ r0, const int* __restrict__ r1,
                             const int* __restrict__ r2, const int* __restrict__ r3,
                             int* __restrict__ counts_all) {
    int mtx = blockIdx.y;
    const int* r = (mtx == 0) ? r0 : (mtx == 1) ? r1 : (mtx == 2) ? r2 : r3;
    int i = blockIdx.x * blockDim.x + threadIdx.x;
    if (i < NNZC) atomicAdd(&counts_all[c_cntoff[mtx] + r[i]], 1);
}

__global__ void scanA4_kernel(const int* __restrict__ counts_all, int* __restrict__ rp_all,
                              int* __restrict__ bsums_all) {
    int mtx = blockIdx.y;
    int n = c_nrows[mtx];
    const int* counts = counts_all + c_cntoff[mtx];
    int* row_ptr = rp_all + c_rpoff[mtx];
    __shared__ int s[256];
    int i = blockIdx.x * 256 + threadIdx.x;
    int v = (i < n) ? counts[i] : 0;
    s[threadIdx.x] = v;
    __syncthreads();
    for (int off = 1; off < 256; off <<= 1) {
        int t = (threadIdx.x >= (unsigned)off) ? s[threadIdx.x - off] : 0;
        __syncthreads();
        s[threadIdx.x] += t;
        __syncthreads();
    }
    if (i < n) row_ptr[i + 1] = s[threadIdx.x];
    if (threadIdx.x == 255) bsums_all[mtx * 512 + blockIdx.x] = s[255];
}

__global__ void scanB4_kernel(int* __restrict__ bsums_all) {
    int* bsums = bsums_all + blockIdx.x * 512;
    __shared__ int s[512];
    int t = threadIdx.x;
    int v = bsums[t];
    s[t] = v;
    __syncthreads();
    for (int off = 1; off < 512; off <<= 1) {
        int u = (t >= off) ? s[t - off] : 0;
        __syncthreads();
        s[t] += u;
        __syncthreads();
    }
    bsums[t] = s[t] - v;  // exclusive
}

__global__ void scanC4_kernel(const int* __restrict__ counts_all, int* __restrict__ rp_all,
                              const int* __restrict__ bsums_all, int* __restrict__ cursor_all) {
    int mtx = blockIdx.y;
    int n = c_nrows[mtx];
    const int* counts = counts_all + c_cntoff[mtx];
    int* row_ptr = rp_all + c_rpoff[mtx];
    int* cursor = cursor_all + c_cntoff[mtx];
    int i = blockIdx.x * 256 + threadIdx.x;
    if (i < n) {
        int f = row_ptr[i + 1] + bsums_all[mtx * 512 + blockIdx.x];
        row_ptr[i + 1] = f;
        cursor[i] = f - counts[i];
    }
    if (i == 0) row_ptr[0] = 0;
}

__global__ void fill4_kernel(const int* __restrict__ r0, const int* __restrict__ r1,
                             const int* __restrict__ r2, const int* __restrict__ r3,
                             const int* __restrict__ c0, const int* __restrict__ c1,
                             const int* __restrict__ c2, const int* __restrict__ c3,
                             const float* __restrict__ v0, const float* __restrict__ v1,
                             const float* __restrict__ v2, const float* __restrict__ v3,
                             int* __restrict__ cursor_all, int2* __restrict__ cpack_all) {
    int mtx = blockIdx.y;
    const int* r = (mtx == 0) ? r0 : (mtx == 1) ? r1 : (mtx == 2) ? r2 : r3;
    const int* c = (mtx == 0) ? c0 : (mtx == 1) ? c1 : (mtx == 2) ? c2 : c3;
    const float* v = (mtx == 0) ? v0 : (mtx == 1) ? v1 : (mtx == 2) ? v2 : v3;
    int i = blockIdx.x * blockDim.x + threadIdx.x;
    if (i < NNZC) {
        int row = r[i];
        int pos = atomicAdd(&cursor_all[c_cntoff[mtx] + row], 1);
        cpack_all[(size_t)mtx * NNZC + pos] = make_int2(c[i], __float_as_int(v[i]));
    }
}

// ---------------- out = (w_di[0]+w_mv[0]) * pois ----------------
__global__ void init_out_kernel(const float* __restrict__ pois, float* __restrict__ out,
                                const float* __restrict__ w, int n) {
    int i = blockIdx.x * blockDim.x + threadIdx.x;
    if (i < n) out[i] = (w[0] + w[4]) * pois[i];
}

// ---------------- fp32 -> packed bf16 cast (pois) ----------------
__global__ void cast_bf16_kernel(const float* __restrict__ src, uint32* __restrict__ dst, int npairs) {
    int i = blockIdx.x * blockDim.x + threadIdx.x;
    if (i < npairs) {
        float2 f = *(const float2*)(src + (size_t)i * 2);
        dst[i] = bfPACK(f.x, f.y);
    }
}

// ---------------- hop1 SpMM: y_bf[row] = A @ x_bf, one wave/row, bf16 gather ----------------
__global__ __launch_bounds__(256) void spmm1_kernel(
    const int* __restrict__ row_ptr, const int2* __restrict__ cp,
    const uint32* __restrict__ xbf, uint32* __restrict__ ybf, int n_rows) {
    int row = (blockIdx.x * blockDim.x + threadIdx.x) >> 6;
    int lane = threadIdx.x & 63;
    if (row >= n_rows) return;
    int start = row_ptr[row], end = row_ptr[row + 1];
    float2 acc = make_float2(0.f, 0.f);
    for (int base = start; base < end; base += 64) {
        int idx = base + lane; if (idx >= end) idx = end - 1;
        int2 cv = cp[idx];
        int nn = min(64, end - base);
        int j = 0;
        for (; j + 4 <= nn; j += 4) {
            int ca = __shfl(cv.x, j),     cb = __shfl(cv.x, j + 1);
            int cc = __shfl(cv.x, j + 2), cd = __shfl(cv.x, j + 3);
            float va = __int_as_float(__shfl(cv.y, j));
            float vb = __int_as_float(__shfl(cv.y, j + 1));
            float vc = __int_as_float(__shfl(cv.y, j + 2));
            float vd = __int_as_float(__shfl(cv.y, j + 3));
            uint32 ua = xbf[(size_t)ca * 64 + lane];
            uint32 ub = xbf[(size_t)cb * 64 + lane];
            uint32 uc = xbf[(size_t)cc * 64 + lane];
            uint32 ud = xbf[(size_t)cd * 64 + lane];
            acc.x = fmaf(va, bfLO(ua), acc.x); acc.y = fmaf(va, bfHI(ua), acc.y);
            acc.x = fmaf(vb, bfLO(ub), acc.x); acc.y = fmaf(vb, bfHI(ub), acc.y);
            acc.x = fmaf(vc, bfLO(uc), acc.x); acc.y = fmaf(vc, bfHI(uc), acc.y);
            acc.x = fmaf(vd, bfLO(ud), acc.x); acc.y = fmaf(vd, bfHI(ud), acc.y);
        }
        for (; j < nn; j++) {
            int cj = __shfl(cv.x, j);
            float vj = __int_as_float(__shfl(cv.y, j));
            uint32 u = xbf[(size_t)cj * 64 + lane];
            acc.x = fmaf(vj, bfLO(u), acc.x);
            acc.y = fmaf(vj, bfHI(u), acc.y);
        }
    }
    ybf[(size_t)row * 64 + lane] = bfPACK(acc.x, acc.y);
}

// ---------------- fused hop2: xnew = relu(A@m)+xin (bf16 chain); out += w*xnew (fp32 RMW) ---------
__global__ __launch_bounds__(256) void spmm2_kernel(
    const int* __restrict__ row_ptr, const int2* __restrict__ cp,
    const uint32* __restrict__ mbf, const uint32* __restrict__ xinbf,
    uint32* __restrict__ xoutbf, float* __restrict__ out,
    const float* __restrict__ wptr, int widx, int n_rows) {
    int row = (blockIdx.x * blockDim.x + threadIdx.x) >> 6;
    int lane = threadIdx.x & 63;
    if (row >= n_rows) return;
    int start = row_ptr[row], end = row_ptr[row + 1];
    float2 acc = make_float2(0.f, 0.f);
    for (int base = start; base < end; base += 64) {
        int idx = base + lane; if (idx >= end) idx = end - 1;
        int2 cv = cp[idx];
        int nn = min(64, end - base);
        int j = 0;
        for (; j + 4 <= nn; j += 4) {
            int ca = __shfl(cv.x, j),     cb = __shfl(cv.x, j + 1);
            int cc = __shfl(cv.x, j + 2), cd = __shfl(cv.x, j + 3);
            float va = __int_as_float(__shfl(cv.y, j));
            float vb = __int_as_float(__shfl(cv.y, j + 1));
            float vc = __int_as_float(__shfl(cv.y, j + 2));
            float vd = __int_as_float(__shfl(cv.y, j + 3));
            uint32 ua = mbf[(size_t)ca * 64 + lane];
            uint32 ub = mbf[(size_t)cb * 64 + lane];
            uint32 uc = mbf[(size_t)cc * 64 + lane];
            uint32 ud = mbf[(size_t)cd * 64 + lane];
            acc.x = fmaf(va, bfLO(ua), acc.x); acc.y = fmaf(va, bfHI(ua), acc.y);
            acc.x = fmaf(vb, bfLO(ub), acc.x); acc.y = fmaf(vb, bfHI(ub), acc.y);
            acc.x = fmaf(vc, bfLO(uc), acc.x); acc.y = fmaf(vc, bfHI(uc), acc.y);
            acc.x = fmaf(vd, bfLO(ud), acc.x); acc.y = fmaf(vd, bfHI(ud), acc.y);
        }
        for (; j < nn; j++) {
            int cj = __shfl(cv.x, j);
            float vj = __int_as_float(__shfl(cv.y, j));
            uint32 u = mbf[(size_t)cj * 64 + lane];
            acc.x = fmaf(vj, bfLO(u), acc.x);
            acc.y = fmaf(vj, bfHI(u), acc.y);
        }
    }
    float w = wptr[widx];
    size_t o32 = (size_t)row * 64 + lane;
    uint32 ui = xinbf[o32];
    float xn0 = fmaxf(acc.x, 0.f) + bfLO(ui);
    float xn1 = fmaxf(acc.y, 0.f) + bfHI(ui);
    xoutbf[o32] = bfPACK(xn0, xn1);
    size_t of = (size_t)row * DIM + lane * 2;
    float2 ov = *(float2*)(out + of);
    ov.x = fmaf(w, xn0, ov.x);
    ov.y = fmaf(w, xn1, ov.y);
    *(float2*)(out + of) = ov;
}

extern "C" void kernel_launch(void* const* d_in, const int* in_sizes, int n_in,
                              void* d_out, int out_size, void* d_ws, size_t ws_size,
                              hipStream_t stream) {
    const float* pois = (const float*)d_in[0];
    const int*   rows_in[4] = { (const int*)d_in[1], (const int*)d_in[4],
                                (const int*)d_in[7], (const int*)d_in[10] };
    const int*   cols_in[4] = { (const int*)d_in[2], (const int*)d_in[5],
                                (const int*)d_in[8], (const int*)d_in[11] };
    const float* vals_in[4] = { (const float*)d_in[3], (const float*)d_in[6],
                                (const float*)d_in[9], (const float*)d_in[12] };
    const float* attn_di = (const float*)d_in[13];
    const float* attn_mv = (const float*)d_in[14];
    float* out = (float*)d_out;

    const int NTOT = NEDGE + NPOI + NUSER + NPOI;  // 300000
    const int rp_off[4]  = { 0, NEDGE + 1, NEDGE + NPOI + 2, NEDGE + NPOI + NUSER + 3 };

    // -------- workspace carve-up (16B-aligned blocks) --------
    char* p = (char*)d_ws;
    float*  wsoft      = (float*)p;  p += 256;
    int*    counts_all = (int*)p;    p += (size_t)NTOT * 4;
    int*    cursor_all = (int*)p;    p += (size_t)NTOT * 4;
    int*    rp_all     = (int*)p;    p += (size_t)(NTOT + 4) * 4;
    p = (char*)(((size_t)p + 15) & ~15ull);
    int*    bsums      = (int*)p;    p += (size_t)4 * 512 * 4;
    int2*   cpack_all  = (int2*)p;   p += (size_t)4 * NNZC * 8;
    uint32* mbf        = (uint32*)p; p += (size_t)NEDGE * 64 * 4;   // 50k rows x 128 bf16
    uint32* poisbf     = (uint32*)p; p += (size_t)NPOI * 64 * 4;
    uint32* xbf        = (uint32*)p; p += (size_t)NPOI * 64 * 4;
    (void)ws_size; (void)out_size; (void)n_in; (void)in_sizes;

    const int gNNZ = ceil_div(NNZC, 256);
    const int nbMax = ceil_div(NPOI, 256);  // 391 (max over the 4 matrices)

    // -------- CSR build (merged across the 4 matrices) --------
    hipMemsetAsync(counts_all, 0, (size_t)NTOT * 4, stream);
    hipMemsetAsync(bsums, 0, (size_t)4 * 512 * 4, stream);
    hist4_kernel<<<dim3(gNNZ, 4), 256, 0, stream>>>(rows_in[0], rows_in[1], rows_in[2], rows_in[3],
                                                    counts_all);
    scanA4_kernel<<<dim3(nbMax, 4), 256, 0, stream>>>(counts_all, rp_all, bsums);
    scanB4_kernel<<<4, 512, 0, stream>>>(bsums);
    scanC4_kernel<<<dim3(nbMax, 4), 256, 0, stream>>>(counts_all, rp_all, bsums, cursor_all);
    fill4_kernel<<<dim3(gNNZ, 4), 256, 0, stream>>>(
        rows_in[0], rows_in[1], rows_in[2], rows_in[3],
        cols_in[0], cols_in[1], cols_in[2], cols_in[3],
        vals_in[0], vals_in[1], vals_in[2], vals_in[3],
        cursor_all, cpack_all);

    // -------- attention weights, output init, bf16 cast of pois --------
    softmax4_kernel<<<1, 64, 0, stream>>>(attn_di, attn_mv, wsoft);
    init_out_kernel<<<ceil_div(NPOI * DIM, 256), 256, 0, stream>>>(pois, out, wsoft, NPOI * DIM);
    cast_bf16_kernel<<<ceil_div(NPOI * 64, 256), 256, 0, stream>>>(pois, poisbf, NPOI * 64);

    // -------- two branches, 3 layers each --------
    for (int br = 0; br < 2; br++) {
        int m1i = br ? 2 : 0;   // up  : tar
        int m2i = br ? 3 : 1;   // pu  : src
        const int* rp1 = rp_all + rp_off[m1i];
        const int* rp2 = rp_all + rp_off[m2i];
        const int2* cp1 = cpack_all + (size_t)m1i * NNZC;
        const int2* cp2 = cpack_all + (size_t)m2i * NNZC;
        const int n1 = 50000;  // NEDGE == NUSER
        const uint32* xcur = poisbf;
        for (int l = 1; l <= NL; l++) {
            spmm1_kernel<<<ceil_div(n1, 4), 256, 0, stream>>>(rp1, cp1, xcur, mbf, n1);
            spmm2_kernel<<<ceil_div(NPOI, 4), 256, 0, stream>>>(
                rp2, cp2, mbf, xcur, xbf, out, wsoft, br * 4 + l, NPOI);
            xcur = xbf;
        }
    }
}

// Round 3
// 1187.396 us; speedup vs baseline: 1.4951x; 1.0636x over previous
//
#include <hip/hip_runtime.h>

#define NNZC   1000000
#define NPOI   100000
#define NEDGE  50000
#define NUSER  50000
#define DIM    128
#define NL     3

static inline int ceil_div(int a, int b) { return (a + b - 1) / b; }

typedef unsigned int uint32;

// ---- bf16 helpers: rows stored as packed pairs (uint32 = 2 bf16, little-endian) ----
__device__ __forceinline__ float bfLO(uint32 u) { return __uint_as_float(u << 16); }
__device__ __forceinline__ float bfHI(uint32 u) { return __uint_as_float(u & 0xffff0000u); }
__device__ __forceinline__ uint32 bf16_rne(float f) {
    uint32 u = __float_as_uint(f);
    return (u + 0x7fffu + ((u >> 16) & 1u)) >> 16;
}
__device__ __forceinline__ uint32 bfPACK(float a, float b) {
    return bf16_rne(a) | (bf16_rne(b) << 16);
}

// per-matrix constants: tar, src, up, pu
__device__ __constant__ const int c_nrows[4]  = { NEDGE, NPOI, NUSER, NPOI };
__device__ __constant__ const int c_cntoff[4] = { 0, NEDGE, NEDGE + NPOI, NEDGE + NPOI + NUSER };
__device__ __constant__ const int c_rpoff[4]  = { 0, NEDGE + 1, NEDGE + NPOI + 2, NEDGE + NPOI + NUSER + 3 };

// ---------------- softmax over the two 4-element attention vectors ----------------
__global__ void softmax4_kernel(const float* __restrict__ adi,
                                const float* __restrict__ amv,
                                float* __restrict__ w) {
    if (blockIdx.x == 0 && threadIdx.x == 0) {
        for (int b = 0; b < 2; b++) {
            const float* a = b ? amv : adi;
            float m = a[0];
            for (int l = 1; l < 4; l++) m = fmaxf(m, a[l]);
            float e[4]; float s = 0.f;
            for (int l = 0; l < 4; l++) { e[l] = __expf(a[l] - m); s += e[l]; }
            for (int l = 0; l < 4; l++) w[b * 4 + l] = e[l] / s;
        }
    }
}

// ---------------- merged CSR build: histogram -> scan -> ranged fill ----------------
__global__ void hist4_kernel(const int* __restrict__ r0, const int* __restrict__ r1,
                             const int* __restrict__ r2, const int* __restrict__ r3,
                             int* __restrict__ counts_all) {
    int mtx = blockIdx.y;
    const int* r = (mtx == 0) ? r0 : (mtx == 1) ? r1 : (mtx == 2) ? r2 : r3;
    int i = blockIdx.x * blockDim.x + threadIdx.x;
    if (i < NNZC) atomicAdd(&counts_all[c_cntoff[mtx] + r[i]], 1);
}

__global__ void scanA4_kernel(const int* __restrict__ counts_all, int* __restrict__ rp_all,
                              int* __restrict__ bsums_all) {
    int mtx = blockIdx.y;
    int n = c_nrows[mtx];
    const int* counts = counts_all + c_cntoff[mtx];
    int* row_ptr = rp_all + c_rpoff[mtx];
    __shared__ int s[256];
    int i = blockIdx.x * 256 + threadIdx.x;
    int v = (i < n) ? counts[i] : 0;
    s[threadIdx.x] = v;
    __syncthreads();
    for (int off = 1; off < 256; off <<= 1) {
        int t = (threadIdx.x >= (unsigned)off) ? s[threadIdx.x - off] : 0;
        __syncthreads();
        s[threadIdx.x] += t;
        __syncthreads();
    }
    if (i < n) row_ptr[i + 1] = s[threadIdx.x];
    if (threadIdx.x == 255) bsums_all[mtx * 512 + blockIdx.x] = s[255];
}

__global__ void scanB4_kernel(int* __restrict__ bsums_all) {
    int* bsums = bsums_all + blockIdx.x * 512;
    __shared__ int s[512];
    int t = threadIdx.x;
    int v = bsums[t];
    s[t] = v;
    __syncthreads();
    for (int off = 1; off < 512; off <<= 1) {
        int u = (t >= off) ? s[t - off] : 0;
        __syncthreads();
        s[t] += u;
        __syncthreads();
    }
    bsums[t] = s[t] - v;  // exclusive
}

__global__ void scanC4_kernel(const int* __restrict__ counts_all, int* __restrict__ rp_all,
                              const int* __restrict__ bsums_all, int* __restrict__ cursor_all) {
    int mtx = blockIdx.y;
    int n = c_nrows[mtx];
    const int* counts = counts_all + c_cntoff[mtx];
    int* row_ptr = rp_all + c_rpoff[mtx];
    int* cursor = cursor_all + c_cntoff[mtx];
    int i = blockIdx.x * 256 + threadIdx.x;
    if (i < n) {
        int f = row_ptr[i + 1] + bsums_all[mtx * 512 + blockIdx.x];
        row_ptr[i + 1] = f;
        cursor[i] = f - counts[i];
    }
    if (i == 0) row_ptr[0] = 0;
}

// Ranged fill: grid.z = 8 row-ranges. Each block streams the COO arrays and only
// scatters entries whose row is in its range -> concurrent scatter confined to a
// ~1MB window that stays L2-resident until lines fill (kills the 8x 64B-line
// write amplification of a full-range random scatter).
__global__ void fillR_kernel(const int* __restrict__ r0, const int* __restrict__ r1,
                             const int* __restrict__ r2, const int* __restrict__ r3,
                             const int* __restrict__ c0, const int* __restrict__ c1,
                             const int* __restrict__ c2, const int* __restrict__ c3,
                             const float* __restrict__ v0, const float* __restrict__ v1,
                             const float* __restrict__ v2, const float* __restrict__ v3,
                             int* __restrict__ cursor_all, int2* __restrict__ cpack_all) {
    int mtx = blockIdx.y;
    int z = blockIdx.z;
    int n = c_nrows[mtx];
    int rlo = (int)(((long long)n * z) >> 3);
    int rhi = (int)(((long long)n * (z + 1)) >> 3);
    const int* r = (mtx == 0) ? r0 : (mtx == 1) ? r1 : (mtx == 2) ? r2 : r3;
    const int* c = (mtx == 0) ? c0 : (mtx == 1) ? c1 : (mtx == 2) ? c2 : c3;
    const float* v = (mtx == 0) ? v0 : (mtx == 1) ? v1 : (mtx == 2) ? v2 : v3;
    int* cursor = cursor_all + c_cntoff[mtx];
    int2* cpack = cpack_all + (size_t)mtx * NNZC;
    int stride = gridDim.x * 256;
    for (int i = blockIdx.x * 256 + threadIdx.x; i < NNZC; i += stride) {
        int row = r[i];
        if (row >= rlo && row < rhi) {
            int pos = atomicAdd(&cursor[row], 1);
            cpack[pos] = make_int2(c[i], __float_as_int(v[i]));
        }
    }
}

// ---------------- fp32 -> packed bf16 cast (pois) ----------------
__global__ void cast_bf16_kernel(const float* __restrict__ src, uint32* __restrict__ dst, int npairs) {
    int i = blockIdx.x * blockDim.x + threadIdx.x;
    if (i < npairs) {
        float2 f = *(const float2*)(src + (size_t)i * 2);
        dst[i] = bfPACK(f.x, f.y);
    }
}

// ---------------- hop1 SpMM: y_bf[row] = A @ x_bf, one wave/row, bf16 gather ----------------
__global__ __launch_bounds__(256) void spmm1_kernel(
    const int* __restrict__ row_ptr, const int2* __restrict__ cp,
    const uint32* __restrict__ xbf, uint32* __restrict__ ybf, int n_rows) {
    int row = (blockIdx.x * blockDim.x + threadIdx.x) >> 6;
    int lane = threadIdx.x & 63;
    if (row >= n_rows) return;
    int start = row_ptr[row], end = row_ptr[row + 1];
    float2 acc = make_float2(0.f, 0.f);
    for (int base = start; base < end; base += 64) {
        int idx = base + lane; if (idx >= end) idx = end - 1;
        int2 cv = cp[idx];
        int nn = min(64, end - base);
        int j = 0;
        for (; j + 4 <= nn; j += 4) {
            int ca = __shfl(cv.x, j),     cb = __shfl(cv.x, j + 1);
            int cc = __shfl(cv.x, j + 2), cd = __shfl(cv.x, j + 3);
            float va = __int_as_float(__shfl(cv.y, j));
            float vb = __int_as_float(__shfl(cv.y, j + 1));
            float vc = __int_as_float(__shfl(cv.y, j + 2));
            float vd = __int_as_float(__shfl(cv.y, j + 3));
            uint32 ua = xbf[(size_t)ca * 64 + lane];
            uint32 ub = xbf[(size_t)cb * 64 + lane];
            uint32 uc = xbf[(size_t)cc * 64 + lane];
            uint32 ud = xbf[(size_t)cd * 64 + lane];
            acc.x = fmaf(va, bfLO(ua), acc.x); acc.y = fmaf(va, bfHI(ua), acc.y);
            acc.x = fmaf(vb, bfLO(ub), acc.x); acc.y = fmaf(vb, bfHI(ub), acc.y);
            acc.x = fmaf(vc, bfLO(uc), acc.x); acc.y = fmaf(vc, bfHI(uc), acc.y);
            acc.x = fmaf(vd, bfLO(ud), acc.x); acc.y = fmaf(vd, bfHI(ud), acc.y);
        }
        for (; j < nn; j++) {
            int cj = __shfl(cv.x, j);
            float vj = __int_as_float(__shfl(cv.y, j));
            uint32 u = xbf[(size_t)cj * 64 + lane];
            acc.x = fmaf(vj, bfLO(u), acc.x);
            acc.y = fmaf(vj, bfHI(u), acc.y);
        }
    }
    ybf[(size_t)row * 64 + lane] = bfPACK(acc.x, acc.y);
}

// ---------------- hop2: xnew = relu(A@m)+xin, bf16 in/out (no `out` RMW here) ----------------
__global__ __launch_bounds__(256) void spmm2_kernel(
    const int* __restrict__ row_ptr, const int2* __restrict__ cp,
    const uint32* __restrict__ mbf, const uint32* __restrict__ xinbf,
    uint32* __restrict__ xoutbf, int n_rows) {
    int row = (blockIdx.x * blockDim.x + threadIdx.x) >> 6;
    int lane = threadIdx.x & 63;
    if (row >= n_rows) return;
    int start = row_ptr[row], end = row_ptr[row + 1];
    float2 acc = make_float2(0.f, 0.f);
    for (int base = start; base < end; base += 64) {
        int idx = base + lane; if (idx >= end) idx = end - 1;
        int2 cv = cp[idx];
        int nn = min(64, end - base);
        int j = 0;
        for (; j + 4 <= nn; j += 4) {
            int ca = __shfl(cv.x, j),     cb = __shfl(cv.x, j + 1);
            int cc = __shfl(cv.x, j + 2), cd = __shfl(cv.x, j + 3);
            float va = __int_as_float(__shfl(cv.y, j));
            float vb = __int_as_float(__shfl(cv.y, j + 1));
            float vc = __int_as_float(__shfl(cv.y, j + 2));
            float vd = __int_as_float(__shfl(cv.y, j + 3));
            uint32 ua = mbf[(size_t)ca * 64 + lane];
            uint32 ub = mbf[(size_t)cb * 64 + lane];
            uint32 uc = mbf[(size_t)cc * 64 + lane];
            uint32 ud = mbf[(size_t)cd * 64 + lane];
            acc.x = fmaf(va, bfLO(ua), acc.x); acc.y = fmaf(va, bfHI(ua), acc.y);
            acc.x = fmaf(vb, bfLO(ub), acc.x); acc.y = fmaf(vb, bfHI(ub), acc.y);
            acc.x = fmaf(vc, bfLO(uc), acc.x); acc.y = fmaf(vc, bfHI(uc), acc.y);
            acc.x = fmaf(vd, bfLO(ud), acc.x); acc.y = fmaf(vd, bfHI(ud), acc.y);
        }
        for (; j < nn; j++) {
            int cj = __shfl(cv.x, j);
            float vj = __int_as_float(__shfl(cv.y, j));
            uint32 u = mbf[(size_t)cj * 64 + lane];
            acc.x = fmaf(vj, bfLO(u), acc.x);
            acc.y = fmaf(vj, bfHI(u), acc.y);
        }
    }
    size_t o32 = (size_t)row * 64 + lane;
    uint32 ui = xinbf[o32];
    float xn0 = fmaxf(acc.x, 0.f) + bfLO(ui);
    float xn1 = fmaxf(acc.y, 0.f) + bfHI(ui);
    xoutbf[o32] = bfPACK(xn0, xn1);
}

// ---------------- epilogues: out = (w0di+w0mv)*pois + sum_l w_l * x_l ----------------
__global__ void epi1_kernel(const float* __restrict__ pois,
                            const uint32* __restrict__ x1, const uint32* __restrict__ x2,
                            const uint32* __restrict__ x3, const float* __restrict__ w,
                            float* __restrict__ out) {
    int i = blockIdx.x * blockDim.x + threadIdx.x;
    if (i < NPOI * 64) {
        float w0 = w[0] + w[4];
        float2 pf = ((const float2*)pois)[i];
        uint32 u1 = x1[i], u2 = x2[i], u3 = x3[i];
        float o0 = w0 * pf.x + w[1] * bfLO(u1) + w[2] * bfLO(u2) + w[3] * bfLO(u3);
        float o1 = w0 * pf.y + w[1] * bfHI(u1) + w[2] * bfHI(u2) + w[3] * bfHI(u3);
        ((float2*)out)[i] = make_float2(o0, o1);
    }
}

__global__ void epi2_kernel(const uint32* __restrict__ x1, const uint32* __restrict__ x2,
                            const uint32* __restrict__ x3, const float* __restrict__ w,
                            float* __restrict__ out) {
    int i = blockIdx.x * blockDim.x + threadIdx.x;
    if (i < NPOI * 64) {
        uint32 u1 = x1[i], u2 = x2[i], u3 = x3[i];
        float2 ov = ((float2*)out)[i];
        ov.x += w[5] * bfLO(u1) + w[6] * bfLO(u2) + w[7] * bfLO(u3);
        ov.y += w[5] * bfHI(u1) + w[6] * bfHI(u2) + w[7] * bfHI(u3);
        ((float2*)out)[i] = ov;
    }
}

extern "C" void kernel_launch(void* const* d_in, const int* in_sizes, int n_in,
                              void* d_out, int out_size, void* d_ws, size_t ws_size,
                              hipStream_t stream) {
    const float* pois = (const float*)d_in[0];
    const int*   rows_in[4] = { (const int*)d_in[1], (const int*)d_in[4],
                                (const int*)d_in[7], (const int*)d_in[10] };
    const int*   cols_in[4] = { (const int*)d_in[2], (const int*)d_in[5],
                                (const int*)d_in[8], (const int*)d_in[11] };
    const float* vals_in[4] = { (const float*)d_in[3], (const float*)d_in[6],
                                (const float*)d_in[9], (const float*)d_in[12] };
    const float* attn_di = (const float*)d_in[13];
    const float* attn_mv = (const float*)d_in[14];
    float* out = (float*)d_out;

    const int NTOT = NEDGE + NPOI + NUSER + NPOI;  // 300000
    const int rp_off[4]  = { 0, NEDGE + 1, NEDGE + NPOI + 2, NEDGE + NPOI + NUSER + 3 };

    // -------- workspace carve-up (16B-aligned blocks) --------
    char* p = (char*)d_ws;
    float*  wsoft      = (float*)p;  p += 256;
    int*    counts_all = (int*)p;    p += (size_t)NTOT * 4;
    int*    cursor_all = (int*)p;    p += (size_t)NTOT * 4;
    int*    rp_all     = (int*)p;    p += (size_t)(NTOT + 4) * 4;
    p = (char*)(((size_t)p + 15) & ~15ull);
    int*    bsums      = (int*)p;    p += (size_t)4 * 512 * 4;
    int2*   cpack_all  = (int2*)p;   p += (size_t)4 * NNZC * 8;
    uint32* mbf        = (uint32*)p; p += (size_t)NEDGE * 64 * 4;   // 50k rows x 128 bf16
    uint32* poisbf     = (uint32*)p; p += (size_t)NPOI * 64 * 4;
    uint32* xl[3];
    for (int l = 0; l < 3; l++) { xl[l] = (uint32*)p; p += (size_t)NPOI * 64 * 4; }
    (void)ws_size; (void)out_size; (void)n_in; (void)in_sizes;

    const int gNNZ = ceil_div(NNZC, 256);
    const int nbMax = ceil_div(NPOI, 256);  // 391 (max over the 4 matrices)

    // -------- CSR build (merged across the 4 matrices) --------
    hipMemsetAsync(counts_all, 0, (size_t)NTOT * 4, stream);
    hipMemsetAsync(bsums, 0, (size_t)4 * 512 * 4, stream);
    hist4_kernel<<<dim3(gNNZ, 4), 256, 0, stream>>>(rows_in[0], rows_in[1], rows_in[2], rows_in[3],
                                                    counts_all);
    scanA4_kernel<<<dim3(nbMax, 4), 256, 0, stream>>>(counts_all, rp_all, bsums);
    scanB4_kernel<<<4, 512, 0, stream>>>(bsums);
    scanC4_kernel<<<dim3(nbMax, 4), 256, 0, stream>>>(counts_all, rp_all, bsums, cursor_all);
    fillR_kernel<<<dim3(64, 4, 8), 256, 0, stream>>>(
        rows_in[0], rows_in[1], rows_in[2], rows_in[3],
        cols_in[0], cols_in[1], cols_in[2], cols_in[3],
        vals_in[0], vals_in[1], vals_in[2], vals_in[3],
        cursor_all, cpack_all);

    // -------- attention weights + bf16 cast of pois --------
    softmax4_kernel<<<1, 64, 0, stream>>>(attn_di, attn_mv, wsoft);
    cast_bf16_kernel<<<ceil_div(NPOI * 64, 256), 256, 0, stream>>>(pois, poisbf, NPOI * 64);

    // -------- two branches, 3 layers each; epilogue per branch --------
    for (int br = 0; br < 2; br++) {
        int m1i = br ? 2 : 0;   // up  : tar
        int m2i = br ? 3 : 1;   // pu  : src
        const int* rp1 = rp_all + rp_off[m1i];
        const int* rp2 = rp_all + rp_off[m2i];
        const int2* cp1 = cpack_all + (size_t)m1i * NNZC;
        const int2* cp2 = cpack_all + (size_t)m2i * NNZC;
        const int n1 = 50000;  // NEDGE == NUSER
        const uint32* xcur = poisbf;
        for (int l = 1; l <= NL; l++) {
            spmm1_kernel<<<ceil_div(n1, 4), 256, 0, stream>>>(rp1, cp1, xcur, mbf, n1);
            spmm2_kernel<<<ceil_div(NPOI, 4), 256, 0, stream>>>(
                rp2, cp2, mbf, xcur, xl[l - 1], NPOI);
            xcur = xl[l - 1];
        }
        if (br == 0)
            epi1_kernel<<<ceil_div(NPOI * 64, 256), 256, 0, stream>>>(
                pois, xl[0], xl[1], xl[2], wsoft, out);
        else
            epi2_kernel<<<ceil_div(NPOI * 64, 256), 256, 0, stream>>>(
                xl[0], xl[1], xl[2], wsoft, out);
    }
}